// Round 6
// baseline (964.010 us; speedup 1.0000x reference)
//
#include <hip/hip_runtime.h>
#include <math.h>

typedef float fx4 __attribute__((ext_vector_type(4)));
#define TPB  256
#define NBLK 1024
#define NG   8            // pipeline groups (B=16 -> GB=2 batches/group)
#define BAR_STRIDE 256    // ints; 1 KB per barrier counter (own cache line)

// ---- init: zero the barrier counters (graph replay re-runs this) ----
__global__ void bitsel_init_kernel(int* __restrict__ bar) {
    if (threadIdx.x < NG) bar[threadIdx.x * BAR_STRIDE] = 0;
}

// ---- persistent pipelined kernel ----
// Stage s: Q(s-1) on L2-hot slice, then R(s) HBM stream, then padded barrier.
// No closer block: every block redundantly computes its batch's head from the
// partials after the barrier (symmetric, contention-free).
__global__ __launch_bounds__(TPB, 4)
void bitsel_persist_kernel(const fx4* __restrict__ x,
                           const float* __restrict__ gf,
                           const float* __restrict__ bits_in,
                           const float* __restrict__ wbits_in,
                           const float* __restrict__ Wl,
                           const float* __restrict__ bl,
                           const float* __restrict__ a1,
                           const float* __restrict__ a2,
                           const float* __restrict__ a3,
                           float* __restrict__ out,
                           fx4* __restrict__ res,
                           int* __restrict__ bar,    // NG counters, padded
                           float* __restrict__ part, // [NG][GB*C][spc][2]
                           int B, int C, int n4, size_t Ntot) {
    const int j   = blockIdx.x;
    const int tid = threadIdx.x;
    const int GB  = B / NG;               // 2 batches per group
    const int GBC = GB * C;               // 128 channels per group
    const int sl4 = (GBC * n4) / NBLK;    // 2048 f4 per block-slice (32 KB)
    const int spc = n4 / sl4;             // 8 sub-slices per channel
    const int ch  = j / spc;              // channel within group [0, GBC)
    const int sub = j % spc;
    const int bpb = NBLK / GB;            // 512 blocks per batch
    const int bl_ = j / bpb;              // batch-local index 0..GB-1

    __shared__ float ssum[4], ssq[4];
    __shared__ float s_std[128];
    __shared__ float s_as[2];

    for (int s = 0; s <= NG; ++s) {
        // ================= Q(s-1): quantize my slice of group s-1 =============
        if (s >= 1) {
            const int g = s - 1;
            const int b = g * GB + bl_;
            // per-channel std from partials (plain loads; acquire done at barrier)
            if (tid < C) {
                const size_t pbase = ((size_t)(g * GBC + bl_ * C + tid)) * spc * 2;
                float S = 0.f, Qq = 0.f;
                #pragma unroll
                for (int p = 0; p < spc; ++p) {
                    S  += part[pbase + 2 * p + 0];
                    Qq += part[pbase + 2 * p + 1];
                }
                const float N = (float)n4 * 4.f;
                float var = (Qq - S * S / N) / (N - 1.f);
                s_std[tid] = sqrtf(fmaxf(var, 0.f));
            }
            __syncthreads();
            if (tid == 0) {
                const int D = C + 2;
                float bt[3];
                for (int kk = 0; kk < 3; ++kk) {
                    float acc = gf[2 * b] * Wl[kk * D] + gf[2 * b + 1] * Wl[kk * D + 1];
                    for (int cc = 0; cc < C; ++cc) acc += s_std[cc] * Wl[kk * D + 2 + cc];
                    bt[kk] = acc + bl[kk];
                }
                int flag = 0; float m = bt[0];
                if (bt[1] > m) { m = bt[1]; flag = 1; }
                if (bt[2] > m) { m = bt[2]; flag = 2; }
                float e0 = expf(bt[0] - m), e1 = expf(bt[1] - m), e2 = expf(bt[2] - m);
                float esum = e0 + e1 + e2;
                float p1 = e0 / esum, p2 = e1 / esum, p3 = e2 / esum;
                float bits_hard = (flag == 0) ? 4.f : (flag == 1) ? 6.f : 8.f;
                float bits_soft = 4.f * p1 + 6.f * p2 + 8.f * p3;
                float bits_out  = (bits_hard - bits_soft) + bits_soft;  // STE fwd
                float denom     = 4.f * p1 + 6.f * p2 + 8.f * p3;
                float alpha = (flag == 0) ? a1[0] : (flag == 1) ? a2[0] : a3[0];
                float a  = fabsf(alpha);
                float sc = (exp2f(bits_hard - 1.f) - 1.f) / a;
                s_as[0] = a; s_as[1] = sc;
                if ((j % bpb) == 0) {  // one block per batch writes tiny outputs
                    out[2 * b]     = gf[2 * b];
                    out[2 * b + 1] = gf[2 * b + 1];
                    out[2 * B + Ntot + b]     = bits_in[b] + bits_out;
                    out[2 * B + Ntot + B + b] = wbits_in[b] + bits_out / denom;
                }
            }
            __syncthreads();
            const float a  = s_as[0];
            const float sc = s_as[1];
            const size_t qbase = (size_t)g * GBC * n4 + (size_t)j * sl4;
            #pragma unroll 4
            for (int i = tid; i < sl4; i += TPB) {
                fx4 v = x[qbase + i];
                fx4 r;
                r.x = rintf(fminf(fmaxf(v.x, -a), a) * sc) / sc;
                r.y = rintf(fminf(fmaxf(v.y, -a), a) * sc) / sc;
                r.z = rintf(fminf(fmaxf(v.z, -a), a) * sc) / sc;
                r.w = rintf(fminf(fmaxf(v.w, -a), a) * sc) / sc;
                __builtin_nontemporal_store(r, &res[qbase + i]);
            }
        }
        if (s == NG) break;  // drain stage: only Q(NG-1)

        // ================= R(s): reduce my slice of group s ====================
        {
            const size_t rbase = (size_t)s * GBC * n4 + (size_t)j * sl4;
            float sum = 0.f, sq = 0.f;
            #pragma unroll 4
            for (int i = tid; i < sl4; i += TPB) {
                fx4 v = x[rbase + i];
                sum += (v.x + v.y) + (v.z + v.w);
                sq  += v.x * v.x + v.y * v.y + v.z * v.z + v.w * v.w;
            }
            for (int off = 32; off > 0; off >>= 1) {
                sum += __shfl_down(sum, off);
                sq  += __shfl_down(sq,  off);
            }
            if ((tid & 63) == 0) { ssum[tid >> 6] = sum; ssq[tid >> 6] = sq; }
            __syncthreads();
            if (tid == 0) {
                float S  = ssum[0] + ssum[1] + ssum[2] + ssum[3];
                float Qq = ssq[0]  + ssq[1]  + ssq[2]  + ssq[3];
                const size_t pidx = ((size_t)(s * GBC + ch) * spc + sub) * 2;
                __hip_atomic_store(&part[pidx + 0], S,
                                   __ATOMIC_RELAXED, __HIP_MEMORY_SCOPE_AGENT);
                __hip_atomic_store(&part[pidx + 1], Qq,
                                   __ATOMIC_RELAXED, __HIP_MEMORY_SCOPE_AGENT);
            }
        }

        // ================= barrier(s): padded, relaxed-spin ====================
        __syncthreads();
        if (tid == 0) {
            int* c = bar + s * BAR_STRIDE;
            __hip_atomic_fetch_add(c, 1, __ATOMIC_RELEASE, __HIP_MEMORY_SCOPE_AGENT);
            while (__hip_atomic_load(c, __ATOMIC_RELAXED,
                                     __HIP_MEMORY_SCOPE_AGENT) < NBLK) {
                __builtin_amdgcn_s_sleep(32);
            }
            (void)__hip_atomic_load(c, __ATOMIC_ACQUIRE, __HIP_MEMORY_SCOPE_AGENT);
        }
        __syncthreads();
    }
}

extern "C" void kernel_launch(void* const* d_in, const int* in_sizes, int n_in,
                              void* d_out, int out_size, void* d_ws, size_t ws_size,
                              hipStream_t stream) {
    const float* x     = (const float*)d_in[0];
    const float* gf    = (const float*)d_in[1];
    const float* bits  = (const float*)d_in[2];
    const float* wbits = (const float*)d_in[3];
    const float* Wl    = (const float*)d_in[4];
    const float* bl    = (const float*)d_in[5];
    const float* a1    = (const float*)d_in[6];
    const float* a2    = (const float*)d_in[7];
    const float* a3    = (const float*)d_in[8];
    float* out = (float*)d_out;

    const int B   = in_sizes[2];              // 16
    const int C   = in_sizes[4] / 3 - 2;      // 64
    const int HWn = in_sizes[0] / (B * C);    // 65536 floats per channel
    const int n4  = HWn / 4;                  // 16384 f4 per channel
    const size_t Ntot = (size_t)in_sizes[0];

    int*   bar  = (int*)d_ws;                         // NG padded counters (8 KB)
    float* part = (float*)(bar + NG * BAR_STRIDE);    // NG*128*8*2 floats (64 KB)
    fx4*   res  = (fx4*)(out + 2 * B);

    bitsel_init_kernel<<<1, 64, 0, stream>>>(bar);

    bitsel_persist_kernel<<<NBLK, TPB, 0, stream>>>(
        (const fx4*)x, gf, bits, wbits, Wl, bl, a1, a2, a3,
        out, res, bar, part, B, C, n4, Ntot);
}

// Round 7
// 324.291 us; speedup vs baseline: 2.9727x; 2.9727x over previous
//
#include <hip/hip_runtime.h>
#include <math.h>

typedef float fx4 __attribute__((ext_vector_type(4)));
#define TPB  256
#define NBLK 1024
#define NG   4            // pipeline groups (B=16 -> GB=4 batches/group)

// ---- init: zero the per-block epoch flags (graph replay re-runs this) ----
__global__ void bitsel_init_kernel(int* __restrict__ flags) {
    flags[threadIdx.x] = 0;   // launched with NBLK threads
}

// ---- persistent pipelined kernel, RMW-free sync ----
// Stage s: R(s) (HBM stream) -> release-store own flag -> poll batch flags
// (coalesced relaxed loads, no RMW anywhere) -> Q(s-1) on cache-hot slice.
// Every block redundantly computes its batch's head from the partials.
__global__ __launch_bounds__(TPB, 4)
void bitsel_persist_kernel(const fx4* __restrict__ x,
                           const float* __restrict__ gf,
                           const float* __restrict__ bits_in,
                           const float* __restrict__ wbits_in,
                           const float* __restrict__ Wl,
                           const float* __restrict__ bl,
                           const float* __restrict__ a1,
                           const float* __restrict__ a2,
                           const float* __restrict__ a3,
                           float* __restrict__ out,
                           fx4* __restrict__ res,
                           int* __restrict__ flags,  // [NBLK] epoch flags
                           float* __restrict__ part, // [NG][GBC][spc][2]
                           int B, int C, int n4, size_t Ntot) {
    const int j   = blockIdx.x;
    const int tid = threadIdx.x;
    const int GB  = B / NG;               // 4 batches per group
    const int GBC = GB * C;               // 256 channels per group
    const int sl4 = (GBC * n4) / NBLK;    // 4096 f4 per block-slice (64 KB)
    const int spc = n4 / sl4;             // 4 sub-slices per channel
    const int ch  = j / spc;              // channel within group [0, GBC)
    const int sub = j % spc;
    const int bpb = NBLK / GB;            // 256 blocks per batch
    const int bl_ = j / bpb;              // batch-local index 0..GB-1

    __shared__ float ssum[4], ssq[4];
    __shared__ float s_std[64];
    __shared__ float s_as[2];

    for (int s = 0; s <= NG; ++s) {
        // ================= R(s): reduce my slice of group s ====================
        if (s < NG) {
            const size_t rbase = (size_t)(s * GBC + ch) * (size_t)n4 + (size_t)sub * sl4;
            float sum = 0.f, sq = 0.f;
            #pragma unroll 4
            for (int i = tid; i < sl4; i += TPB) {
                fx4 v = x[rbase + i];
                sum += (v.x + v.y) + (v.z + v.w);
                sq  += v.x * v.x + v.y * v.y + v.z * v.z + v.w * v.w;
            }
            for (int off = 32; off > 0; off >>= 1) {
                sum += __shfl_down(sum, off);
                sq  += __shfl_down(sq,  off);
            }
            __syncthreads();   // protect shared reuse across stages
            if ((tid & 63) == 0) { ssum[tid >> 6] = sum; ssq[tid >> 6] = sq; }
            __syncthreads();
            if (tid == 0) {
                float S  = ssum[0] + ssum[1] + ssum[2] + ssum[3];
                float Qq = ssq[0]  + ssq[1]  + ssq[2]  + ssq[3];
                const size_t pidx = ((size_t)(s * GBC + ch) * spc + sub) * 2;
                part[pidx + 0] = S;
                part[pidx + 1] = Qq;
                // release store orders the partial stores; distinct address per
                // block -> plain pipelined stores, NO serialized RMWs.
                __hip_atomic_store(&flags[j], s + 1,
                                   __ATOMIC_RELEASE, __HIP_MEMORY_SCOPE_AGENT);
            }
        }
        // ================= Q(s-1): quantize my slice of group s-1 ==============
        if (s >= 1) {
            const int g = s - 1;
            const int b = g * GB + bl_;
            // ---- wait for all 256 blocks of my batch to finish R(g) ----
            // coalesced: 256 threads read 256 contiguous flags (8 cache lines)
            for (;;) {
                int ok = __hip_atomic_load(&flags[bl_ * bpb + tid],
                                           __ATOMIC_RELAXED,
                                           __HIP_MEMORY_SCOPE_AGENT) >= s;
                if (__syncthreads_and(ok)) break;
                __builtin_amdgcn_s_sleep(32);
            }
            __builtin_amdgcn_fence(__ATOMIC_ACQUIRE, "agent");  // order + L1 inv

            // ---- per-channel std from partials (redundant per block) ----
            if (tid < C) {
                const size_t pbase = ((size_t)(g * GBC + bl_ * C + tid)) * spc * 2;
                float S = 0.f, Qq = 0.f;
                #pragma unroll
                for (int p = 0; p < spc; ++p) {
                    S  += part[pbase + 2 * p + 0];
                    Qq += part[pbase + 2 * p + 1];
                }
                const float N = (float)n4 * 4.f;
                float var = (Qq - S * S / N) / (N - 1.f);
                s_std[tid] = sqrtf(fmaxf(var, 0.f));
            }
            __syncthreads();
            if (tid == 0) {
                const int D = C + 2;
                float bt[3];
                for (int kk = 0; kk < 3; ++kk) {
                    float acc = gf[2 * b] * Wl[kk * D] + gf[2 * b + 1] * Wl[kk * D + 1];
                    for (int cc = 0; cc < C; ++cc) acc += s_std[cc] * Wl[kk * D + 2 + cc];
                    bt[kk] = acc + bl[kk];
                }
                int flag = 0; float m = bt[0];
                if (bt[1] > m) { m = bt[1]; flag = 1; }
                if (bt[2] > m) { m = bt[2]; flag = 2; }
                float e0 = expf(bt[0] - m), e1 = expf(bt[1] - m), e2 = expf(bt[2] - m);
                float esum = e0 + e1 + e2;
                float p1 = e0 / esum, p2 = e1 / esum, p3 = e2 / esum;
                float bits_hard = (flag == 0) ? 4.f : (flag == 1) ? 6.f : 8.f;
                float bits_soft = 4.f * p1 + 6.f * p2 + 8.f * p3;
                float bits_out  = (bits_hard - bits_soft) + bits_soft;  // STE fwd
                float denom     = 4.f * p1 + 6.f * p2 + 8.f * p3;
                float alpha = (flag == 0) ? a1[0] : (flag == 1) ? a2[0] : a3[0];
                float a  = fabsf(alpha);
                float sc = (exp2f(bits_hard - 1.f) - 1.f) / a;
                s_as[0] = a; s_as[1] = sc;
                if ((j % bpb) == 0) {  // one block per batch writes tiny outputs
                    out[2 * b]     = gf[2 * b];
                    out[2 * b + 1] = gf[2 * b + 1];
                    out[2 * B + Ntot + b]     = bits_in[b] + bits_out;
                    out[2 * B + Ntot + B + b] = wbits_in[b] + bits_out / denom;
                }
            }
            __syncthreads();
            const float a  = s_as[0];
            const float sc = s_as[1];
            // same slice this block reduced one stage ago -> L2/L3-hot
            const size_t qbase = (size_t)(g * GBC + ch) * (size_t)n4 + (size_t)sub * sl4;
            #pragma unroll 4
            for (int i = tid; i < sl4; i += TPB) {
                fx4 v = x[qbase + i];
                fx4 r;
                r.x = rintf(fminf(fmaxf(v.x, -a), a) * sc) / sc;
                r.y = rintf(fminf(fmaxf(v.y, -a), a) * sc) / sc;
                r.z = rintf(fminf(fmaxf(v.z, -a), a) * sc) / sc;
                r.w = rintf(fminf(fmaxf(v.w, -a), a) * sc) / sc;
                __builtin_nontemporal_store(r, &res[qbase + i]);
            }
        }
    }
}

extern "C" void kernel_launch(void* const* d_in, const int* in_sizes, int n_in,
                              void* d_out, int out_size, void* d_ws, size_t ws_size,
                              hipStream_t stream) {
    const float* x     = (const float*)d_in[0];
    const float* gf    = (const float*)d_in[1];
    const float* bits  = (const float*)d_in[2];
    const float* wbits = (const float*)d_in[3];
    const float* Wl    = (const float*)d_in[4];
    const float* bl    = (const float*)d_in[5];
    const float* a1    = (const float*)d_in[6];
    const float* a2    = (const float*)d_in[7];
    const float* a3    = (const float*)d_in[8];
    float* out = (float*)d_out;

    const int B   = in_sizes[2];              // 16
    const int C   = in_sizes[4] / 3 - 2;      // 64
    const int HWn = in_sizes[0] / (B * C);    // 65536 floats per channel
    const int n4  = HWn / 4;                  // 16384 f4 per channel
    const size_t Ntot = (size_t)in_sizes[0];

    int*   flags = (int*)d_ws;                // NBLK ints (4 KB)
    float* part  = (float*)(flags + NBLK);    // NG*GBC*spc*2 floats (32 KB)
    fx4*   res   = (fx4*)(out + 2 * B);

    bitsel_init_kernel<<<1, NBLK, 0, stream>>>(flags);

    bitsel_persist_kernel<<<NBLK, TPB, 0, stream>>>(
        (const fx4*)x, gf, bits, wbits, Wl, bl, a1, a2, a3,
        out, res, flags, part, B, C, n4, Ntot);
}

// Round 8
// 142.672 us; speedup vs baseline: 6.7568x; 2.2730x over previous
//
#include <hip/hip_runtime.h>
#include <math.h>

typedef float fx4 __attribute__((ext_vector_type(4)));
#define TPB  256
#define NBLK 1024   // slices per group (R and Q use the same slicing)

// Unified R/Q kernel. G=2 groups of 8 batches (134 MB each).
// mode 0: R-only  (block j -> R slice j of group gR)          [fill]
// mode 1: interleaved (even j -> Q slice j/2 of gQ,
//                      odd  j -> R slice j/2 of gR)           [middle]
// mode 2: Q-only  (block j -> Q slice j of group gQ)          [drain]
// Slice k of group g = f4 range [k*sl4, (k+1)*sl4) within the group --
// IDENTICAL mapping for R and Q, so the Q block re-reads exactly what the
// same-index R block streamed one launch earlier (L3-resident, partly L2).
// Q blocks redundantly compute their batch's head from the partials
// (kernel boundary provides ordering + visibility; no atomics anywhere).
__global__ __launch_bounds__(TPB)
void bitsel_rq_kernel(const fx4* __restrict__ x,
                      const float* __restrict__ gf,
                      const float* __restrict__ bits_in,
                      const float* __restrict__ wbits_in,
                      const float* __restrict__ Wl,
                      const float* __restrict__ bl,
                      const float* __restrict__ a1,
                      const float* __restrict__ a2,
                      const float* __restrict__ a3,
                      float* __restrict__ out,
                      fx4* __restrict__ res,
                      float* __restrict__ part,  // [2][GBC][spc][2]
                      int gR, int gQ, int mode,
                      int B, int C, int n4, size_t Ntot) {
    const int j   = blockIdx.x;
    const int tid = threadIdx.x;
    const int GB  = B / 2;               // 8 batches per group
    const int GBC = GB * C;              // 512 channels per group
    const int sl4 = (GBC * n4) / NBLK;   // 8192 f4 per slice (128 KB)
    const int spc = n4 / sl4;            // 2 slices per channel
    const int bpb = NBLK / GB;           // 128 slices (blocks) per batch

    int isR, slice;
    if (mode == 0)      { isR = 1;     slice = j;      }
    else if (mode == 2) { isR = 0;     slice = j;      }
    else                { isR = j & 1; slice = j >> 1; }

    if (isR) {
        // ---------------- R: reduce slice of group gR ----------------
        const int ch  = slice / spc;
        const int sub = slice % spc;
        const size_t base = (size_t)(gR * GBC + ch) * (size_t)n4 + (size_t)sub * sl4;
        float sum = 0.f, sq = 0.f;
        #pragma unroll 4
        for (int i = tid; i < sl4; i += TPB) {
            fx4 v = x[base + i];
            sum += (v.x + v.y) + (v.z + v.w);
            sq  += v.x * v.x + v.y * v.y + v.z * v.z + v.w * v.w;
        }
        for (int off = 32; off > 0; off >>= 1) {
            sum += __shfl_down(sum, off);
            sq  += __shfl_down(sq,  off);
        }
        __shared__ float ssum[4], ssq[4];
        if ((tid & 63) == 0) { ssum[tid >> 6] = sum; ssq[tid >> 6] = sq; }
        __syncthreads();
        if (tid == 0) {
            float S  = ssum[0] + ssum[1] + ssum[2] + ssum[3];
            float Qq = ssq[0]  + ssq[1]  + ssq[2]  + ssq[3];
            const size_t pidx = ((size_t)(gR * GBC + ch) * spc + sub) * 2;
            part[pidx + 0] = S;
            part[pidx + 1] = Qq;
        }
    } else {
        // ---------------- Q: quantize slice of group gQ ----------------
        const int bl_ = slice / bpb;            // batch-local 0..GB-1
        const int b   = gQ * GB + bl_;

        __shared__ float s_std[64];
        __shared__ float s_as[2];

        if (tid < C) {
            const size_t pbase = ((size_t)(gQ * GBC + bl_ * C + tid)) * spc * 2;
            float S = 0.f, Qq = 0.f;
            #pragma unroll
            for (int p = 0; p < spc; ++p) {
                S  += part[pbase + 2 * p + 0];
                Qq += part[pbase + 2 * p + 1];
            }
            const float N = (float)n4 * 4.f;
            float var = (Qq - S * S / N) / (N - 1.f);
            s_std[tid] = sqrtf(fmaxf(var, 0.f));
        }
        __syncthreads();
        if (tid == 0) {
            const int D = C + 2;
            float bt[3];
            for (int kk = 0; kk < 3; ++kk) {
                float acc = gf[2 * b] * Wl[kk * D] + gf[2 * b + 1] * Wl[kk * D + 1];
                for (int cc = 0; cc < C; ++cc) acc += s_std[cc] * Wl[kk * D + 2 + cc];
                bt[kk] = acc + bl[kk];
            }
            int flag = 0; float m = bt[0];
            if (bt[1] > m) { m = bt[1]; flag = 1; }
            if (bt[2] > m) { m = bt[2]; flag = 2; }
            float e0 = expf(bt[0] - m), e1 = expf(bt[1] - m), e2 = expf(bt[2] - m);
            float esum = e0 + e1 + e2;
            float p1 = e0 / esum, p2 = e1 / esum, p3 = e2 / esum;
            float bits_hard = (flag == 0) ? 4.f : (flag == 1) ? 6.f : 8.f;
            float bits_soft = 4.f * p1 + 6.f * p2 + 8.f * p3;
            float bits_out  = (bits_hard - bits_soft) + bits_soft;  // STE fwd
            float denom     = 4.f * p1 + 6.f * p2 + 8.f * p3;
            float alpha = (flag == 0) ? a1[0] : (flag == 1) ? a2[0] : a3[0];
            float a  = fabsf(alpha);
            float sc = (exp2f(bits_hard - 1.f) - 1.f) / a;
            s_as[0] = a; s_as[1] = sc;
            if ((slice % bpb) == 0) {  // one block per batch: tiny outputs
                out[2 * b]     = gf[2 * b];
                out[2 * b + 1] = gf[2 * b + 1];
                out[2 * B + Ntot + b]     = bits_in[b] + bits_out;
                out[2 * B + Ntot + B + b] = wbits_in[b] + bits_out / denom;
            }
        }
        __syncthreads();
        const float a  = s_as[0];
        const float sc = s_as[1];
        const size_t base = (size_t)gQ * GBC * (size_t)n4 + (size_t)slice * sl4;
        #pragma unroll 4
        for (int i = tid; i < sl4; i += TPB) {
            fx4 v = x[base + i];
            fx4 r;
            r.x = rintf(fminf(fmaxf(v.x, -a), a) * sc) / sc;
            r.y = rintf(fminf(fmaxf(v.y, -a), a) * sc) / sc;
            r.z = rintf(fminf(fmaxf(v.z, -a), a) * sc) / sc;
            r.w = rintf(fminf(fmaxf(v.w, -a), a) * sc) / sc;
            __builtin_nontemporal_store(r, &res[base + i]);
        }
    }
}

extern "C" void kernel_launch(void* const* d_in, const int* in_sizes, int n_in,
                              void* d_out, int out_size, void* d_ws, size_t ws_size,
                              hipStream_t stream) {
    const float* x     = (const float*)d_in[0];
    const float* gf    = (const float*)d_in[1];
    const float* bits  = (const float*)d_in[2];
    const float* wbits = (const float*)d_in[3];
    const float* Wl    = (const float*)d_in[4];
    const float* bl    = (const float*)d_in[5];
    const float* a1    = (const float*)d_in[6];
    const float* a2    = (const float*)d_in[7];
    const float* a3    = (const float*)d_in[8];
    float* out = (float*)d_out;

    const int B   = in_sizes[2];              // 16
    const int C   = in_sizes[4] / 3 - 2;      // 64
    const int HWn = in_sizes[0] / (B * C);    // 65536 floats per channel
    const int n4  = HWn / 4;                  // 16384 f4 per channel
    const size_t Ntot = (size_t)in_sizes[0];

    float* part = (float*)d_ws;               // 2*GBC*spc*2 floats (16 KB)
    fx4*   res  = (fx4*)(out + 2 * B);

    // fill: R(0)
    bitsel_rq_kernel<<<NBLK, TPB, 0, stream>>>(
        (const fx4*)x, gf, bits, wbits, Wl, bl, a1, a2, a3,
        out, res, part, 0, -1, 0, B, C, n4, Ntot);
    // middle: R(1) + Q(0), interleaved blocks
    bitsel_rq_kernel<<<2 * NBLK, TPB, 0, stream>>>(
        (const fx4*)x, gf, bits, wbits, Wl, bl, a1, a2, a3,
        out, res, part, 1, 0, 1, B, C, n4, Ntot);
    // drain: Q(1)
    bitsel_rq_kernel<<<NBLK, TPB, 0, stream>>>(
        (const fx4*)x, gf, bits, wbits, Wl, bl, a1, a2, a3,
        out, res, part, -1, 1, 2, B, C, n4, Ntot);
}

// Round 9
// 138.119 us; speedup vs baseline: 6.9796x; 1.0330x over previous
//
#include <hip/hip_runtime.h>
#include <math.h>

typedef float fx4 __attribute__((ext_vector_type(4)));
#define TPB 256
#define SL4 4096          // f4 per slice (64 KB) -- proven in R4
#define SPC 4             // slices per channel = n4 / SL4 (16384/4096)

// Unified R/Q kernel with uneven batch groups {4,6,6}:
//   blocks [0, nQblk)        : Q slices of batches [bQ0, bQ0+nQb)
//   blocks [nQblk, gridDim)  : R slices of batches [bR0, ...)
// Slice-in-batch mapping identical for R and Q (256 slices/batch), so the Q
// block re-reads exactly what an R block streamed one launch earlier
// (L3-resident; per-middle touched set kept < 256 MB).
// Q blocks redundantly compute their batch's head from the partials.
// Launch seq: R(0-3); Q(0-3)+R(4-9); Q(4-9)+R(10-15); Q(10-15)
__global__ __launch_bounds__(TPB)
void bitsel_rq_kernel(const fx4* __restrict__ x,
                      const float* __restrict__ gf,
                      const float* __restrict__ bits_in,
                      const float* __restrict__ wbits_in,
                      const float* __restrict__ Wl,
                      const float* __restrict__ bl,
                      const float* __restrict__ a1,
                      const float* __restrict__ a2,
                      const float* __restrict__ a3,
                      float* __restrict__ out,
                      fx4* __restrict__ res,
                      float* __restrict__ part,  // [B][C][SPC][2] (global batch)
                      int bR0, int bQ0, int nQblk,
                      int B, int C, int n4, size_t Ntot) {
    const int tid = threadIdx.x;
    const int spb = C * SPC;              // slices per batch (256)

    if ((int)blockIdx.x >= nQblk) {
        // ---------------- R: reduce one slice ----------------
        const int slice = (int)blockIdx.x - nQblk;
        const int b   = bR0 + slice / spb;
        const int sib = slice % spb;
        const int ch  = sib / SPC;
        const int sub = sib % SPC;
        const size_t base = (size_t)(b * C + ch) * (size_t)n4 + (size_t)sub * SL4;
        float sum = 0.f, sq = 0.f;
        #pragma unroll 4
        for (int i = tid; i < SL4; i += TPB) {
            fx4 v = x[base + i];
            sum += (v.x + v.y) + (v.z + v.w);
            sq  += v.x * v.x + v.y * v.y + v.z * v.z + v.w * v.w;
        }
        for (int off = 32; off > 0; off >>= 1) {
            sum += __shfl_down(sum, off);
            sq  += __shfl_down(sq,  off);
        }
        __shared__ float ssum[4], ssq[4];
        if ((tid & 63) == 0) { ssum[tid >> 6] = sum; ssq[tid >> 6] = sq; }
        __syncthreads();
        if (tid == 0) {
            float S  = ssum[0] + ssum[1] + ssum[2] + ssum[3];
            float Qq = ssq[0]  + ssq[1]  + ssq[2]  + ssq[3];
            const size_t pidx = ((size_t)(b * C + ch) * SPC + sub) * 2;
            part[pidx + 0] = S;
            part[pidx + 1] = Qq;
        }
    } else {
        // ---------------- Q: quantize one slice ----------------
        const int slice = (int)blockIdx.x;
        const int b   = bQ0 + slice / spb;
        const int sib = slice % spb;

        __shared__ float s_std[64];
        __shared__ float s_as[2];

        if (tid < C) {
            const size_t pbase = ((size_t)(b * C + tid)) * SPC * 2;
            float S = 0.f, Qq = 0.f;
            #pragma unroll
            for (int p = 0; p < SPC; ++p) {
                S  += part[pbase + 2 * p + 0];
                Qq += part[pbase + 2 * p + 1];
            }
            const float N = (float)n4 * 4.f;
            float var = (Qq - S * S / N) / (N - 1.f);
            s_std[tid] = sqrtf(fmaxf(var, 0.f));
        }
        __syncthreads();
        if (tid == 0) {
            const int D = C + 2;
            float bt[3];
            for (int kk = 0; kk < 3; ++kk) {
                float acc = gf[2 * b] * Wl[kk * D] + gf[2 * b + 1] * Wl[kk * D + 1];
                for (int cc = 0; cc < C; ++cc) acc += s_std[cc] * Wl[kk * D + 2 + cc];
                bt[kk] = acc + bl[kk];
            }
            int flag = 0; float m = bt[0];
            if (bt[1] > m) { m = bt[1]; flag = 1; }
            if (bt[2] > m) { m = bt[2]; flag = 2; }
            float e0 = expf(bt[0] - m), e1 = expf(bt[1] - m), e2 = expf(bt[2] - m);
            float esum = e0 + e1 + e2;
            float p1 = e0 / esum, p2 = e1 / esum, p3 = e2 / esum;
            float bits_hard = (flag == 0) ? 4.f : (flag == 1) ? 6.f : 8.f;
            float bits_soft = 4.f * p1 + 6.f * p2 + 8.f * p3;
            float bits_out  = (bits_hard - bits_soft) + bits_soft;  // STE fwd
            float denom     = 4.f * p1 + 6.f * p2 + 8.f * p3;
            float alpha = (flag == 0) ? a1[0] : (flag == 1) ? a2[0] : a3[0];
            float a  = fabsf(alpha);
            float sc = (exp2f(bits_hard - 1.f) - 1.f) / a;
            s_as[0] = a; s_as[1] = sc;
            if (sib == 0) {  // one block per batch writes the tiny outputs
                out[2 * b]     = gf[2 * b];
                out[2 * b + 1] = gf[2 * b + 1];
                out[2 * B + Ntot + b]     = bits_in[b] + bits_out;
                out[2 * B + Ntot + B + b] = wbits_in[b] + bits_out / denom;
            }
        }
        __syncthreads();
        const float a  = s_as[0];
        const float sc = s_as[1];
        const int ch  = sib / SPC;
        const int sub = sib % SPC;
        const size_t base = (size_t)(b * C + ch) * (size_t)n4 + (size_t)sub * SL4;
        #pragma unroll 4
        for (int i = tid; i < SL4; i += TPB) {
            fx4 v = __builtin_nontemporal_load(&x[base + i]);  // L3-hit, no re-promote
            fx4 r;
            r.x = rintf(fminf(fmaxf(v.x, -a), a) * sc) / sc;
            r.y = rintf(fminf(fmaxf(v.y, -a), a) * sc) / sc;
            r.z = rintf(fminf(fmaxf(v.z, -a), a) * sc) / sc;
            r.w = rintf(fminf(fmaxf(v.w, -a), a) * sc) / sc;
            __builtin_nontemporal_store(r, &res[base + i]);
        }
    }
}

extern "C" void kernel_launch(void* const* d_in, const int* in_sizes, int n_in,
                              void* d_out, int out_size, void* d_ws, size_t ws_size,
                              hipStream_t stream) {
    const float* x     = (const float*)d_in[0];
    const float* gf    = (const float*)d_in[1];
    const float* bits  = (const float*)d_in[2];
    const float* wbits = (const float*)d_in[3];
    const float* Wl    = (const float*)d_in[4];
    const float* bl    = (const float*)d_in[5];
    const float* a1    = (const float*)d_in[6];
    const float* a2    = (const float*)d_in[7];
    const float* a3    = (const float*)d_in[8];
    float* out = (float*)d_out;

    const int B   = in_sizes[2];              // 16
    const int C   = in_sizes[4] / 3 - 2;      // 64
    const int HWn = in_sizes[0] / (B * C);    // 65536 floats per channel
    const int n4  = HWn / 4;                  // 16384 f4 per channel
    const size_t Ntot = (size_t)in_sizes[0];
    const int spb = C * SPC;                  // 256 slices (blocks) per batch

    float* part = (float*)d_ws;               // B*C*SPC*2 floats (32 KB)
    fx4*   res  = (fx4*)(out + 2 * B);

    // Groups {4,6,6}: every middle's L3 touched-set <= 200 MB < 256 MB.
    const int g0 = 4, g1 = 6, g2 = 6;

    // L1: R(0..3)
    bitsel_rq_kernel<<<g0 * spb, TPB, 0, stream>>>(
        (const fx4*)x, gf, bits, wbits, Wl, bl, a1, a2, a3,
        out, res, part, /*bR0=*/0, /*bQ0=*/0, /*nQblk=*/0, B, C, n4, Ntot);
    // L2: Q(0..3) + R(4..9)
    bitsel_rq_kernel<<<g0 * spb + g1 * spb, TPB, 0, stream>>>(
        (const fx4*)x, gf, bits, wbits, Wl, bl, a1, a2, a3,
        out, res, part, /*bR0=*/g0, /*bQ0=*/0, /*nQblk=*/g0 * spb, B, C, n4, Ntot);
    // L3: Q(4..9) + R(10..15)
    bitsel_rq_kernel<<<g1 * spb + g2 * spb, TPB, 0, stream>>>(
        (const fx4*)x, gf, bits, wbits, Wl, bl, a1, a2, a3,
        out, res, part, /*bR0=*/g0 + g1, /*bQ0=*/g0, /*nQblk=*/g1 * spb, B, C, n4, Ntot);
    // L4: Q(10..15)
    bitsel_rq_kernel<<<g2 * spb, TPB, 0, stream>>>(
        (const fx4*)x, gf, bits, wbits, Wl, bl, a1, a2, a3,
        out, res, part, /*bR0=*/0, /*bQ0=*/g0 + g1, /*nQblk=*/g2 * spb, B, C, n4, Ntot);
}